// Round 1
// baseline (544.543 us; speedup 1.0000x reference)
//
#include <hip/hip_runtime.h>
#include <stdint.h>

// ---------- types ----------
typedef __attribute__((ext_vector_type(4))) float  f32x4;
typedef __attribute__((ext_vector_type(8))) short  short8;   // 8 bf16 in 4 VGPRs
typedef __attribute__((ext_vector_type(4))) short  short4v;  // 4 bf16, 8B

#define MFMA16(a,b,c) __builtin_amdgcn_mfma_f32_16x16x32_bf16((a),(b),(c),0,0,0)

static __device__ __forceinline__ unsigned short f2bf(float f) {
    unsigned int u = __float_as_uint(f);
    u += 0x7FFFu + ((u >> 16) & 1u);   // round-to-nearest-even
    return (unsigned short)(u >> 16);
}

// B=2, S=2048, C=512, E=512, H=8, HD=64
// qlin[b,s,e] reshaped (B,H,S,HD) without transpose:
//   q[b,h,i,d] = qlin_flat[b*1048576 + h*131072 + i*64 + d]
// => per (b,h): contiguous [2048][64] slab.

// =====================================================================
// Kernel 1: fused QKV projection.  Y[m,e] = sum_c x[m,c]*W[e,c] + b[e]
// M=4096, N=512 per W (3 Ws => grid.y = 12), K=512. NT GEMM (both K-contig).
// Outputs: Qb, Kb as bf16 [4096][512]; V written transposed per head:
//   Vt[(b*8+h)*64 + d][s2]  (row stride 2048)
// =====================================================================
__global__ __launch_bounds__(256) void qkv_gemm(
    const float* __restrict__ x,
    const float* __restrict__ Wq, const float* __restrict__ bq,
    const float* __restrict__ Wk, const float* __restrict__ bk,
    const float* __restrict__ Wv, const float* __restrict__ bv,
    unsigned short* __restrict__ Qb, unsigned short* __restrict__ Kb,
    unsigned short* __restrict__ Vt)
{
    __shared__ unsigned short As[128 * 40];  // stride 40 bf16 = 80B (16B-mult, conflict-free)
    __shared__ unsigned short Bs[128 * 40];

    const int tid  = threadIdx.x;
    const int lane = tid & 63;
    const int wid  = tid >> 6;
    const int g = lane >> 4, c = lane & 15;
    const int wr = wid >> 1, wc = wid & 1;
    const int bm    = blockIdx.x;        // 0..31
    const int widx  = blockIdx.y >> 2;   // 0..2  (Q/K/V)
    const int ntile = blockIdx.y & 3;    // 0..3

    const float* W    = (widx == 0) ? Wq : (widx == 1) ? Wk : Wv;
    const float* bias = (widx == 0) ? bq : (widx == 1) ? bk : bv;
    const float* Abase = x + (size_t)bm * 128 * 512;
    const float* Bbase = W + (size_t)ntile * 128 * 512;

    f32x4 acc[4][4];
    #pragma unroll
    for (int m = 0; m < 4; m++)
        #pragma unroll
        for (int n = 0; n < 4; n++) acc[m][n] = (f32x4){0.f, 0.f, 0.f, 0.f};

    for (int kk = 0; kk < 512; kk += 32) {
        // stage A and B tiles (128x32 fp32 -> bf16)
        #pragma unroll
        for (int i = 0; i < 4; i++) {
            int f  = i * 256 + tid;      // float4 id, 1024 total
            int rr = f >> 3;             // row 0..127
            int cc = (f & 7) * 4;        // col 0..28
            f32x4 va = *(const f32x4*)(Abase + rr * 512 + kk + cc);
            f32x4 vb = *(const f32x4*)(Bbase + rr * 512 + kk + cc);
            short4v sa, sb;
            #pragma unroll
            for (int q = 0; q < 4; q++) { sa[q] = (short)f2bf(va[q]); sb[q] = (short)f2bf(vb[q]); }
            *(short4v*)(&As[rr * 40 + cc]) = sa;
            *(short4v*)(&Bs[rr * 40 + cc]) = sb;
        }
        __syncthreads();

        short8 af[4], bfr[4];
        #pragma unroll
        for (int m = 0; m < 4; m++) af[m]  = *(const short8*)(&As[(wr * 64 + m * 16 + c) * 40 + g * 8]);
        #pragma unroll
        for (int n = 0; n < 4; n++) bfr[n] = *(const short8*)(&Bs[(wc * 64 + n * 16 + c) * 40 + g * 8]);
        #pragma unroll
        for (int m = 0; m < 4; m++)
            #pragma unroll
            for (int n = 0; n < 4; n++)
                acc[m][n] = MFMA16(af[m], bfr[n], acc[m][n]);
        __syncthreads();
    }

    // epilogue: C layout col=lane&15, row=(lane>>4)*4+reg
    #pragma unroll
    for (int n = 0; n < 4; n++) {
        int colW = ntile * 128 + wc * 64 + n * 16 + c;
        float bb = bias[colW];
        #pragma unroll
        for (int m = 0; m < 4; m++) {
            #pragma unroll
            for (int r = 0; r < 4; r++) {
                int row = bm * 128 + wr * 64 + m * 16 + g * 4 + r;   // 0..4095
                unsigned short h16 = f2bf(acc[m][n][r] + bb);
                if (widx == 0)      Qb[(size_t)row * 512 + colW] = h16;
                else if (widx == 1) Kb[(size_t)row * 512 + colW] = h16;
                else {
                    int b   = row >> 11, s = row & 2047;
                    int flat = s * 512 + colW;            // head-view flat index
                    int h   = flat >> 17;
                    int rem = flat & 131071;
                    int s2  = rem >> 6, d = rem & 63;
                    Vt[((size_t)(b * 8 + h) * 64 + d) * 2048 + s2] = h16;
                }
            }
        }
    }
}

// =====================================================================
// Kernel 2: fused attention.
// grid (32 qtiles, 16 bh), block 256 (4 waves). Each wave owns 16 q rows,
// fully independent -> no barriers. Two passes over 32 key-blocks of 64:
//   pass 1: QK^T (MFMA) -> online row max + denom (shfl_xor over 16 lanes)
//   pass 2: recompute QK^T, p=exp(l-m)/d, ap=0.5*(p+dist), store ap,
//           LDS round-trip ap (C-layout -> A-frag layout), PV MFMA accumulate.
// ctx written bf16 into ctx_bf[b*2048+i][h*64+d]  (the transpose(0,2,1,3) layout)
// =====================================================================
__global__ __launch_bounds__(256) void attn_kernel(
    const unsigned short* __restrict__ Qb, const unsigned short* __restrict__ Kb,
    const unsigned short* __restrict__ Vt,
    const float* __restrict__ dist, const int* __restrict__ mask,
    float* __restrict__ attn_out, unsigned short* __restrict__ ctx_bf)
{
    __shared__ unsigned short AP[4][16][72];   // per-wave P tile, stride 72 bf16 = 144B

    const int tid = threadIdx.x;
    const int lane = tid & 63, wid = tid >> 6;
    const int g = lane >> 4, c = lane & 15;
    const int qt = blockIdx.x;       // 0..31
    const int bh = blockIdx.y;       // 0..15
    const int b = bh >> 3, h = bh & 7;

    const unsigned short* Qh  = Qb + (size_t)b * 1048576 + (size_t)h * 131072;
    const unsigned short* Kh  = Kb + (size_t)b * 1048576 + (size_t)h * 131072;
    const unsigned short* Vth = Vt + (size_t)bh * 131072;       // [64 d][2048 s]
    const float* distb = dist + (size_t)bh * 4194304;
    float*       outb  = attn_out + (size_t)bh * 4194304;
    const int*   maskb = mask + b * 2048;

    const int qrow = qt * 64 + wid * 16;      // head-local base of this wave's rows

    short8 qf[2];
    #pragma unroll
    for (int ks = 0; ks < 2; ks++)
        qf[ks] = *(const short8*)(Qh + (size_t)(qrow + c) * 64 + ks * 32 + g * 8);

    float mrow[4], drow[4];
    #pragma unroll
    for (int r = 0; r < 4; r++) { mrow[r] = -1e30f; drow[r] = 0.f; }

    // ---------------- pass 1: max + denom ----------------
    for (int kb = 0; kb < 2048; kb += 64) {
        short8 kf[4][2];
        #pragma unroll
        for (int n = 0; n < 4; n++)
            #pragma unroll
            for (int ks = 0; ks < 2; ks++)
                kf[n][ks] = *(const short8*)(Kh + (size_t)(kb + n * 16 + c) * 64 + ks * 32 + g * 8);
        f32x4 s[4];
        #pragma unroll
        for (int n = 0; n < 4; n++) {
            f32x4 z = (f32x4){0.f, 0.f, 0.f, 0.f};
            z = MFMA16(qf[0], kf[n][0], z);
            z = MFMA16(qf[1], kf[n][1], z);
            s[n] = z;
        }
        float l[4][4];
        #pragma unroll
        for (int n = 0; n < 4; n++) {
            int mv = maskb[kb + n * 16 + c];
            #pragma unroll
            for (int r = 0; r < 4; r++)
                l[n][r] = mv ? -1250.f : s[n][r] * 0.125f;
        }
        #pragma unroll
        for (int r = 0; r < 4; r++) {
            float lm = fmaxf(fmaxf(l[0][r], l[1][r]), fmaxf(l[2][r], l[3][r]));
            for (int off = 1; off < 16; off <<= 1) lm = fmaxf(lm, __shfl_xor(lm, off));
            float nm = fmaxf(mrow[r], lm);
            float ps = __expf(l[0][r] - nm) + __expf(l[1][r] - nm)
                     + __expf(l[2][r] - nm) + __expf(l[3][r] - nm);
            for (int off = 1; off < 16; off <<= 1) ps += __shfl_xor(ps, off);
            drow[r] = drow[r] * __expf(mrow[r] - nm) + ps;
            mrow[r] = nm;
        }
    }
    float invd[4];
    #pragma unroll
    for (int r = 0; r < 4; r++) invd[r] = 1.f / drow[r];

    // ---------------- pass 2: probs + store + PV ----------------
    f32x4 cacc[4];
    #pragma unroll
    for (int nd = 0; nd < 4; nd++) cacc[nd] = (f32x4){0.f, 0.f, 0.f, 0.f};

    for (int kb = 0; kb < 2048; kb += 64) {
        short8 kf[4][2];
        #pragma unroll
        for (int n = 0; n < 4; n++)
            #pragma unroll
            for (int ks = 0; ks < 2; ks++)
                kf[n][ks] = *(const short8*)(Kh + (size_t)(kb + n * 16 + c) * 64 + ks * 32 + g * 8);
        f32x4 s[4];
        #pragma unroll
        for (int n = 0; n < 4; n++) {
            f32x4 z = (f32x4){0.f, 0.f, 0.f, 0.f};
            z = MFMA16(qf[0], kf[n][0], z);
            z = MFMA16(qf[1], kf[n][1], z);
            s[n] = z;
        }
        #pragma unroll
        for (int n = 0; n < 4; n++) {
            int key = kb + n * 16 + c;
            int mv  = maskb[key];
            #pragma unroll
            for (int r = 0; r < 4; r++) {
                float lv = mv ? -1250.f : s[n][r] * 0.125f;
                float p  = __expf(lv - mrow[r]) * invd[r];
                size_t off = (size_t)(qrow + g * 4 + r) * 2048 + key;
                float ap = 0.5f * (p + distb[off]);
                outb[off] = ap;
                AP[wid][g * 4 + r][n * 16 + c] = f2bf(ap);
            }
        }
        // LDS round-trip: read A-frags of P (compiler orders ds_write->ds_read)
        short8 apf[2];
        #pragma unroll
        for (int ks = 0; ks < 2; ks++)
            apf[ks] = *(const short8*)(&AP[wid][c][ks * 32 + g * 8]);
        #pragma unroll
        for (int nd = 0; nd < 4; nd++) {
            #pragma unroll
            for (int ks = 0; ks < 2; ks++) {
                short8 vf = *(const short8*)(Vth + (size_t)(nd * 16 + c) * 2048 + kb + ks * 32 + g * 8);
                cacc[nd] = MFMA16(apf[ks], vf, cacc[nd]);
            }
        }
    }

    // store ctx in (B,S,E) layout: out row b*2048+i, col h*64+d
    #pragma unroll
    for (int nd = 0; nd < 4; nd++) {
        #pragma unroll
        for (int r = 0; r < 4; r++) {
            int i = qrow + g * 4 + r;
            ctx_bf[(size_t)(b * 2048 + i) * 512 + h * 64 + nd * 16 + c] = f2bf(cacc[nd][r]);
        }
    }
}

// =====================================================================
// Kernel 3: out = ctx @ Wo^T + bo.  A bf16 [4096][512], B fp32 [512][512] (NT).
// =====================================================================
__global__ __launch_bounds__(256) void out_gemm(
    const unsigned short* __restrict__ A,
    const float* __restrict__ Wo, const float* __restrict__ bo,
    float* __restrict__ out)
{
    __shared__ unsigned short As[128 * 40];
    __shared__ unsigned short Bs[128 * 40];

    const int tid  = threadIdx.x;
    const int lane = tid & 63;
    const int wid  = tid >> 6;
    const int g = lane >> 4, c = lane & 15;
    const int wr = wid >> 1, wc = wid & 1;
    const int bm    = blockIdx.x;   // 0..31
    const int ntile = blockIdx.y;   // 0..3

    const unsigned short* Abase = A + (size_t)bm * 128 * 512;
    const float* Bbase = Wo + (size_t)ntile * 128 * 512;

    f32x4 acc[4][4];
    #pragma unroll
    for (int m = 0; m < 4; m++)
        #pragma unroll
        for (int n = 0; n < 4; n++) acc[m][n] = (f32x4){0.f, 0.f, 0.f, 0.f};

    for (int kk = 0; kk < 512; kk += 32) {
        #pragma unroll
        for (int i = 0; i < 2; i++) {          // A: 4096 bf16, 16B per thread x2
            int f8 = i * 256 + tid;            // short8 id, 512 total
            int rr = f8 >> 2;
            int cc = (f8 & 3) * 8;
            short8 va = *(const short8*)(Abase + (size_t)rr * 512 + kk + cc);
            *(short8*)(&As[rr * 40 + cc]) = va;
        }
        #pragma unroll
        for (int i = 0; i < 4; i++) {          // B: fp32 -> bf16
            int f  = i * 256 + tid;
            int rr = f >> 3;
            int cc = (f & 7) * 4;
            f32x4 vb = *(const f32x4*)(Bbase + (size_t)rr * 512 + kk + cc);
            short4v sb;
            #pragma unroll
            for (int q = 0; q < 4; q++) sb[q] = (short)f2bf(vb[q]);
            *(short4v*)(&Bs[rr * 40 + cc]) = sb;
        }
        __syncthreads();

        short8 af[4], bfr[4];
        #pragma unroll
        for (int m = 0; m < 4; m++) af[m]  = *(const short8*)(&As[(wr * 64 + m * 16 + c) * 40 + g * 8]);
        #pragma unroll
        for (int n = 0; n < 4; n++) bfr[n] = *(const short8*)(&Bs[(wc * 64 + n * 16 + c) * 40 + g * 8]);
        #pragma unroll
        for (int m = 0; m < 4; m++)
            #pragma unroll
            for (int n = 0; n < 4; n++)
                acc[m][n] = MFMA16(af[m], bfr[n], acc[m][n]);
        __syncthreads();
    }

    #pragma unroll
    for (int n = 0; n < 4; n++) {
        int col = ntile * 128 + wc * 64 + n * 16 + c;
        float bb = bo[col];
        #pragma unroll
        for (int m = 0; m < 4; m++) {
            #pragma unroll
            for (int r = 0; r < 4; r++) {
                int row = bm * 128 + wr * 64 + m * 16 + g * 4 + r;
                out[(size_t)row * 512 + col] = acc[m][n][r] + bb;
            }
        }
    }
}

// =====================================================================
extern "C" void kernel_launch(void* const* d_in, const int* in_sizes, int n_in,
                              void* d_out, int out_size, void* d_ws, size_t ws_size,
                              hipStream_t stream)
{
    const float* x    = (const float*)d_in[0];
    const float* dist = (const float*)d_in[1];
    const int*   mask = (const int*)d_in[2];
    const float* Wq   = (const float*)d_in[3];
    const float* bq   = (const float*)d_in[4];
    const float* Wk   = (const float*)d_in[5];
    const float* bk   = (const float*)d_in[6];
    const float* Wv   = (const float*)d_in[7];
    const float* bv   = (const float*)d_in[8];
    const float* Wo   = (const float*)d_in[9];
    const float* bo   = (const float*)d_in[10];

    float* out      = (float*)d_out;            // (2,2048,512)   = 2,097,152
    float* attn_out = out + 2097152;            // (2,8,2048,2048)= 67,108,864

    char* ws = (char*)d_ws;
    unsigned short* Qb  = (unsigned short*)(ws);                 // 4 MB
    unsigned short* Kb  = (unsigned short*)(ws + (4u << 20));    // 4 MB
    unsigned short* Vt  = (unsigned short*)(ws + (8u << 20));    // 4 MB  [16][64][2048]
    unsigned short* ctx = (unsigned short*)(ws + (12u << 20));   // 4 MB  [4096][512]

    qkv_gemm  <<<dim3(32, 12), 256, 0, stream>>>(x, Wq, bq, Wk, bk, Wv, bv, Qb, Kb, Vt);
    attn_kernel<<<dim3(32, 16), 256, 0, stream>>>(Qb, Kb, Vt, dist, mask, attn_out, ctx);
    out_gemm  <<<dim3(32, 4),  256, 0, stream>>>(ctx, Wo, bo, out);
}